// Round 11
// baseline (97.299 us; speedup 1.0000x reference)
//
#include <hip/hip_runtime.h>
#include <hip/hip_bf16.h>
#include <cmath>

#define B_ 4
#define T_ 2048
#define C_ 1024
#define H_ 64
#define K2_ 0.04508422003f       /* (1024^-0.5) * log2(e) */
#define THRRAW_ 177.0f           /* defer-max threshold: 8 / K2_ */
#define NEG_ -3.0e38f

typedef __attribute__((ext_vector_type(4))) float f32x4;
typedef __attribute__((ext_vector_type(8))) short s16x8;
typedef __attribute__((ext_vector_type(4))) unsigned short u16x4;
typedef __attribute__((ext_vector_type(8))) unsigned short u16x8;

__device__ inline unsigned short f2bf(float f) {
    union { __hip_bfloat16 h; unsigned short u; } cv;
    cv.h = __float2bfloat16(f);
    return cv.u;
}

#define LDK 72  /* padded k-stride in bf16 elems */

// ---------------- W prep: Wt[c][k] = bf16(W[mat][k][col]), c = mat*64+col ----
__global__ __launch_bounds__(256) void wprep(
    const float* __restrict__ Wq, const float* __restrict__ Wk,
    const float* __restrict__ Wv, unsigned short* __restrict__ wt)
{
    const int g = blockIdx.x * 256 + threadIdx.x;
    const int c = g >> 7;             // 0..191, wave-uniform
    const int kg = (g & 127) * 8;
    const float* W = (c < 64) ? Wq : (c < 128) ? Wk : Wv;
    const int col = c & 63;
    u16x4 a, b;
    a.x = f2bf(W[(size_t)(kg + 0) * H_ + col]);
    a.y = f2bf(W[(size_t)(kg + 1) * H_ + col]);
    a.z = f2bf(W[(size_t)(kg + 2) * H_ + col]);
    a.w = f2bf(W[(size_t)(kg + 3) * H_ + col]);
    b.x = f2bf(W[(size_t)(kg + 4) * H_ + col]);
    b.y = f2bf(W[(size_t)(kg + 5) * H_ + col]);
    b.z = f2bf(W[(size_t)(kg + 6) * H_ + col]);
    b.w = f2bf(W[(size_t)(kg + 7) * H_ + col]);
    *(u16x4*)&wt[(size_t)c * C_ + kg] = a;
    *(u16x4*)&wt[(size_t)c * C_ + kg + 4] = b;
}

// ---------------- projection (R10 logic) + x3 replication for counters -------
// rep = blk/384 selects output set (rep0 = real, rep1/2 = ws scratch).
__global__ __launch_bounds__(256, 4) void proj_dbuf(
    const float* __restrict__ x, const unsigned short* __restrict__ wt,
    unsigned short* __restrict__ qb0, unsigned short* __restrict__ kb0,
    unsigned short* __restrict__ vt0, unsigned short* __restrict__ scr)
{
    __shared__ alignas(16) unsigned short As[2][64 * LDK];   // [buf][row][k]
    __shared__ alignas(16) unsigned short Bs[2][64 * LDK];   // [buf][col][k]

    const int t = threadIdx.x, lane = t & 63, w = t >> 6;
    const int rep = blockIdx.x / 384;
    const int blk = blockIdx.x % 384;
    unsigned short* qb = (rep == 0) ? qb0 : scr + (size_t)(rep - 1) * 4194304;
    unsigned short* kb = qb + 524288;
    unsigned short* vt = qb + 1048576;
    const int mat = blk % 3;
    const int row0 = (blk / 3) * 64;
    const int wr = (w >> 1) * 32, wc = (w & 1) * 32;
    const int fr = lane & 15, ko = (lane >> 4) * 8;

    const int ar0 = t >> 4, akc = (t & 15) * 4;   // A: 4 rows x 16B, coalesced
    const int bc0 = t >> 3, bkc = (t & 7) * 8;    // B: 2 cols x 16B (8 bf16)

    const float* xp = x + (size_t)(row0 + ar0) * C_ + akc;
    const unsigned short* wp = wt + (size_t)(mat * 64 + bc0) * C_ + bkc;

    f32x4 pa[4];
    u16x8 pb[2];

    #pragma unroll
    for (int i = 0; i < 4; ++i) pa[i] = *(const f32x4*)(xp + (size_t)i * 16 * C_);
    #pragma unroll
    for (int i = 0; i < 2; ++i) pb[i] = *(const u16x8*)(wp + (size_t)i * 32 * C_);
    #pragma unroll
    for (int i = 0; i < 4; ++i) {
        u16x4 bv;
        bv.x = f2bf(pa[i].x); bv.y = f2bf(pa[i].y);
        bv.z = f2bf(pa[i].z); bv.w = f2bf(pa[i].w);
        *(u16x4*)&As[0][(ar0 + i * 16) * LDK + akc] = bv;
    }
    #pragma unroll
    for (int i = 0; i < 2; ++i)
        *(u16x8*)&Bs[0][(bc0 + i * 32) * LDK + bkc] = pb[i];

    f32x4 acc[2][2];
    #pragma unroll
    for (int mi = 0; mi < 2; ++mi)
        #pragma unroll
        for (int ni = 0; ni < 2; ++ni)
            acc[mi][ni] = (f32x4){0.f, 0.f, 0.f, 0.f};

    for (int it = 0; it < 16; ++it) {
        __syncthreads();
        const int cur = it & 1;
        if (it < 15) {
            const float* xn = xp + (it + 1) * 64;
            const unsigned short* wn = wp + (it + 1) * 64;
            #pragma unroll
            for (int i = 0; i < 4; ++i) pa[i] = *(const f32x4*)(xn + (size_t)i * 16 * C_);
            #pragma unroll
            for (int i = 0; i < 2; ++i) pb[i] = *(const u16x8*)(wn + (size_t)i * 32 * C_);
        }
        const unsigned short* A = &As[cur][0];
        const unsigned short* Bb = &Bs[cur][0];
        #pragma unroll
        for (int ks = 0; ks < 2; ++ks) {
            s16x8 a0 = *(const s16x8*)&A[(wr + fr) * LDK + ks * 32 + ko];
            s16x8 a1 = *(const s16x8*)&A[(wr + 16 + fr) * LDK + ks * 32 + ko];
            s16x8 b0 = *(const s16x8*)&Bb[(wc + fr) * LDK + ks * 32 + ko];
            s16x8 b1 = *(const s16x8*)&Bb[(wc + 16 + fr) * LDK + ks * 32 + ko];
            acc[0][0] = __builtin_amdgcn_mfma_f32_16x16x32_bf16(a0, b0, acc[0][0], 0, 0, 0);
            acc[0][1] = __builtin_amdgcn_mfma_f32_16x16x32_bf16(a0, b1, acc[0][1], 0, 0, 0);
            acc[1][0] = __builtin_amdgcn_mfma_f32_16x16x32_bf16(a1, b0, acc[1][0], 0, 0, 0);
            acc[1][1] = __builtin_amdgcn_mfma_f32_16x16x32_bf16(a1, b1, acc[1][1], 0, 0, 0);
        }
        if (it < 15) {
            const int nxt = cur ^ 1;
            #pragma unroll
            for (int i = 0; i < 4; ++i) {
                u16x4 bv;
                bv.x = f2bf(pa[i].x); bv.y = f2bf(pa[i].y);
                bv.z = f2bf(pa[i].z); bv.w = f2bf(pa[i].w);
                *(u16x4*)&As[nxt][(ar0 + i * 16) * LDK + akc] = bv;
            }
            #pragma unroll
            for (int i = 0; i < 2; ++i)
                *(u16x8*)&Bs[nxt][(bc0 + i * 32) * LDK + bkc] = pb[i];
        }
    }

    // ---- epilogue. C/D: col = lane&15, row = (lane>>4)*4+reg ----
    if (mat < 2) {
        unsigned short* outb = (mat == 0) ? qb : kb;
        #pragma unroll
        for (int mi = 0; mi < 2; ++mi)
            #pragma unroll
            for (int ni = 0; ni < 2; ++ni)
                #pragma unroll
                for (int j = 0; j < 4; ++j) {
                    int row = row0 + wr + mi * 16 + (lane >> 4) * 4 + j;
                    int col = wc + ni * 16 + fr;
                    outb[(size_t)row * H_ + col] = f2bf(acc[mi][ni][j]);
                }
    } else {
        __syncthreads();
        unsigned short* Tr = &As[0][0];
        #pragma unroll
        for (int mi = 0; mi < 2; ++mi)
            #pragma unroll
            for (int ni = 0; ni < 2; ++ni)
                #pragma unroll
                for (int j = 0; j < 4; ++j) {
                    int r = wr + mi * 16 + (lane >> 4) * 4 + j;
                    int cc = wc + ni * 16 + fr;
                    Tr[cc * LDK + r] = f2bf(acc[mi][ni][j]);
                }
        __syncthreads();
        int h = t >> 2, c0 = (t & 3) * 16;
        int bb = row0 >> 11, trow = row0 & 2047;
        s16x8 v0 = *(const s16x8*)&Tr[h * LDK + c0];
        s16x8 v1 = *(const s16x8*)&Tr[h * LDK + c0 + 8];
        size_t dst = (size_t)bb * H_ * T_ + (size_t)h * T_ + trow + c0;
        *(s16x8*)&vt[dst] = v0;
        *(s16x8*)&vt[dst + 8] = v1;
    }
}

// ---------------- MFMA flash attention (R10 logic) + x3 replication ----------
__global__ __launch_bounds__(512, 4) void attn_mfma(
    const unsigned short* __restrict__ qb, const unsigned short* __restrict__ kb,
    const unsigned short* __restrict__ vt, float* __restrict__ o0,
    float* __restrict__ o1, float* __restrict__ o2)
{
    __shared__ alignas(16) unsigned short Ps[8][1024];  // per-wave P (swizzled)
    __shared__ float Os[8][16][68];
    __shared__ float Mm[8][16];
    __shared__ float Ll[8][16];

    const int t = threadIdx.x, lane = t & 63, w = t >> 6;
    const int fr = lane & 15, hi4 = lane >> 4;
    const int rep = blockIdx.x >> 9;
    const int blk = blockIdx.x & 511;
    float* outp = (rep == 0) ? o0 : (rep == 1) ? o1 : o2;
    const int b = blk & 3;
    const int qt = 127 - (blk >> 2);     // big q-tiles dispatch first
    const int qbase = qt * 16;

    const unsigned short* qp = qb + ((size_t)b * T_ + qbase) * H_;
    const unsigned short* kp = kb + (size_t)b * T_ * H_;
    const unsigned short* vp = vt + (size_t)b * H_ * T_;

    s16x8 qf0 = *(const s16x8*)&qp[fr * H_ + hi4 * 8];
    s16x8 qf1 = *(const s16x8*)&qp[fr * H_ + 32 + hi4 * 8];

    const int nt = (qbase + 79) >> 6;
    const int per = (nt + 7) >> 3;
    const int tb = w * per;
    int te = tb + per; if (te > nt) te = nt;

    float m = NEG_, l = 0.f;
    f32x4 o[4];
    #pragma unroll
    for (int hf = 0; hf < 4; ++hf) o[hf] = (f32x4){0.f, 0.f, 0.f, 0.f};

    unsigned short* P = &Ps[w][0];
    const int swz = (fr & 3) << 4;
    const int qrow = qbase + fr;

    for (int kt = tb; kt < te; ++kt) {
        const int kt0 = kt << 6;

        f32x4 s[4];
        #pragma unroll
        for (int n = 0; n < 4; ++n) {
            const unsigned short* kr = &kp[(size_t)(kt0 + n * 16 + fr) * H_ + hi4 * 8];
            s16x8 kf0 = *(const s16x8*)kr;
            s16x8 kf1 = *(const s16x8*)(kr + 32);
            f32x4 a = (f32x4){0.f, 0.f, 0.f, 0.f};
            a = __builtin_amdgcn_mfma_f32_16x16x32_bf16(kf0, qf0, a, 0, 0, 0);
            a = __builtin_amdgcn_mfma_f32_16x16x32_bf16(kf1, qf1, a, 0, 0, 0);
            s[n] = a;
        }

        s16x8 vf[4][2];
        #pragma unroll
        for (int hf = 0; hf < 4; ++hf) {
            const unsigned short* vr = &vp[(size_t)(hf * 16 + fr) * T_ + kt0 + hi4 * 8];
            vf[hf][0] = *(const s16x8*)vr;
            vf[hf][1] = *(const s16x8*)(vr + 32);
        }

        if (kt0 + 63 > qbase) {
            #pragma unroll
            for (int n = 0; n < 4; ++n)
                #pragma unroll
                for (int j = 0; j < 4; ++j) {
                    int key = kt0 + n * 16 + hi4 * 4 + j;
                    s[n][j] = (key > qrow) ? NEG_ : s[n][j];
                }
        }

        float mxl = fmaxf(fmaxf(fmaxf(fmaxf(s[0][0], s[0][1]), fmaxf(s[0][2], s[0][3])),
                                fmaxf(fmaxf(s[1][0], s[1][1]), fmaxf(s[1][2], s[1][3]))),
                          fmaxf(fmaxf(fmaxf(s[2][0], s[2][1]), fmaxf(s[2][2], s[2][3])),
                                fmaxf(fmaxf(s[3][0], s[3][1]), fmaxf(s[3][2], s[3][3]))));
        if (!__all(mxl - m <= THRRAW_)) {
            float mx = fmaxf(mxl, __shfl_xor(mxl, 16));
            mx = fmaxf(mx, __shfl_xor(mx, 32));
            float mn = fmaxf(m, mx);
            float corr = exp2f((m - mn) * K2_);
            m = mn;
            l *= corr;
            #pragma unroll
            for (int j = 0; j < 4; ++j) {
                float cj = __shfl(corr, (lane & 48) + hi4 * 4 + j);
                o[0][j] *= cj; o[1][j] *= cj; o[2][j] *= cj; o[3][j] *= cj;
            }
        }
        const float nmk = -m * K2_;
        float sum = 0.f;
        #pragma unroll
        for (int n = 0; n < 4; ++n)
            #pragma unroll
            for (int j = 0; j < 4; ++j) {
                float p = exp2f(fmaf(s[n][j], K2_, nmk));
                s[n][j] = p; sum += p;
            }
        sum += __shfl_xor(sum, 16);
        sum += __shfl_xor(sum, 32);
        l += sum;

        #pragma unroll
        for (int n = 0; n < 4; ++n) {
            u16x4 pk;
            pk.x = f2bf(s[n][0]); pk.y = f2bf(s[n][1]);
            pk.z = f2bf(s[n][2]); pk.w = f2bf(s[n][3]);
            *(u16x4*)&P[fr * 64 + ((n * 16 + hi4 * 4) ^ swz)] = pk;
        }
        s16x8 pa0 = *(const s16x8*)&P[fr * 64 + ((hi4 * 8) ^ swz)];
        s16x8 pa1 = *(const s16x8*)&P[fr * 64 + ((32 + hi4 * 8) ^ swz)];

        #pragma unroll
        for (int hf = 0; hf < 4; ++hf) {
            o[hf] = __builtin_amdgcn_mfma_f32_16x16x32_bf16(pa0, vf[hf][0], o[hf], 0, 0, 0);
            o[hf] = __builtin_amdgcn_mfma_f32_16x16x32_bf16(pa1, vf[hf][1], o[hf], 0, 0, 0);
        }
    }

    if (hi4 == 0) { Mm[w][fr] = m; Ll[w][fr] = l; }
    #pragma unroll
    for (int hf = 0; hf < 4; ++hf)
        #pragma unroll
        for (int j = 0; j < 4; ++j)
            Os[w][hi4 * 4 + j][hf * 16 + fr] = o[hf][j];
    __syncthreads();

    if (t < 256) {
        int qq = t >> 4, h0 = (t & 15) * 4;
        float M = NEG_;
        #pragma unroll
        for (int s8 = 0; s8 < 8; ++s8) M = fmaxf(M, Mm[s8][qq]);
        float L = 0.f;
        f32x4 r = (f32x4){0.f, 0.f, 0.f, 0.f};
        #pragma unroll
        for (int s8 = 0; s8 < 8; ++s8) {
            float e = exp2f((Mm[s8][qq] - M) * K2_);
            L += Ll[s8][qq] * e;
            f32x4 osv = *(const f32x4*)&Os[s8][qq][h0];
            r.x = fmaf(osv.x, e, r.x);
            r.y = fmaf(osv.y, e, r.y);
            r.z = fmaf(osv.z, e, r.z);
            r.w = fmaf(osv.w, e, r.w);
        }
        float il = 1.0f / L;
        r.x *= il; r.y *= il; r.z *= il; r.w *= il;
        *(f32x4*)&outp[((size_t)b * T_ + qbase + qq) * H_ + h0] = r;
    }
}

extern "C" void kernel_launch(void* const* d_in, const int* in_sizes, int n_in,
                              void* d_out, int out_size, void* d_ws, size_t ws_size,
                              hipStream_t stream) {
    const float* x  = (const float*)d_in[0];
    const float* Wq = (const float*)d_in[1];
    const float* Wk = (const float*)d_in[2];
    const float* Wv = (const float*)d_in[3];
    float* outp = (float*)d_out;

    unsigned short* base = (unsigned short*)d_ws;
    unsigned short* qbw = base;                    // [8192][64]
    unsigned short* kbw = base + 524288;           // [8192][64]
    unsigned short* vtw = base + 1048576;          // [4][64][2048]
    unsigned short* wtw = base + 1572864;          // [192][1024]
    unsigned short* pscr = base + 4194304;         // proj replica outs (8MB, 16MB off)
    float* ascr1 = (float*)(base + 33554432);      // attn replica outs (64MB off)
    float* ascr2 = (float*)(base + 50331648);      // (96MB off)

    wprep<<<96, 256, 0, stream>>>(Wq, Wk, Wv, wtw);
    // DIAGNOSTIC x3 replication (this round): forces both kernels above the
    // ~41us fill dispatches so rocprof top-5 finally shows their counters.
    // Per-unit = counters/3. Replicas write disjoint ws scratch; rep0 is real.
    proj_dbuf<<<384 * 3, 256, 0, stream>>>(x, wtw, qbw, kbw, vtw, pscr);
    attn_mfma<<<512 * 3, 512, 0, stream>>>(qbw, kbw, vtw, outp, ascr1, ascr2);
}

// Round 12
// 53.970 us; speedup vs baseline: 1.8028x; 1.8028x over previous
//
#include <hip/hip_runtime.h>
#include <hip/hip_bf16.h>
#include <cmath>

#define B_ 4
#define T_ 2048
#define C_ 1024
#define H_ 64
#define K2_ 0.04508422003f       /* (1024^-0.5) * log2(e) */
#define THRRAW_ 177.0f           /* defer-max threshold: 8 / K2_ */
#define NEG_ -3.0e38f

typedef __attribute__((ext_vector_type(4))) float f32x4;
typedef __attribute__((ext_vector_type(8))) short s16x8;
typedef __attribute__((ext_vector_type(4))) unsigned short u16x4;
typedef __attribute__((ext_vector_type(8))) unsigned short u16x8;

__device__ inline unsigned short f2bf(float f) {
    union { __hip_bfloat16 h; unsigned short u; } cv;
    cv.h = __float2bfloat16(f);
    return cv.u;
}

#define LDK 72  /* padded k-stride in bf16 elems */

// ---------------- W prep: Wt[c][k] = bf16(W[mat][k][col]), c = mat*64+col ----
__global__ __launch_bounds__(256) void wprep(
    const float* __restrict__ Wq, const float* __restrict__ Wk,
    const float* __restrict__ Wv, unsigned short* __restrict__ wt)
{
    const int g = blockIdx.x * 256 + threadIdx.x;
    const int c = g >> 7;             // 0..191, wave-uniform
    const int kg = (g & 127) * 8;
    const float* W = (c < 64) ? Wq : (c < 128) ? Wk : Wv;
    const int col = c & 63;
    u16x4 a, b;
    a.x = f2bf(W[(size_t)(kg + 0) * H_ + col]);
    a.y = f2bf(W[(size_t)(kg + 1) * H_ + col]);
    a.z = f2bf(W[(size_t)(kg + 2) * H_ + col]);
    a.w = f2bf(W[(size_t)(kg + 3) * H_ + col]);
    b.x = f2bf(W[(size_t)(kg + 4) * H_ + col]);
    b.y = f2bf(W[(size_t)(kg + 5) * H_ + col]);
    b.z = f2bf(W[(size_t)(kg + 6) * H_ + col]);
    b.w = f2bf(W[(size_t)(kg + 7) * H_ + col]);
    *(u16x4*)&wt[(size_t)c * C_ + kg] = a;
    *(u16x4*)&wt[(size_t)c * C_ + kg + 4] = b;
}

// ---------------- projection: 32x64 tiles, grid 768, LDS double-buffer ------
// R12: tile rows 64->32 doubles block count (1.5 -> 3 blocks/CU) — R11 showed
// proj was latency-bound at 1.5 blocks/CU. Staging ledger: A 256thr x 2 x 16B
// = 8KB = 32x64 f32 ✓; B 2 x 16B = 8KB = 64x64 bf16 ✓. LDS 27.6 KB.
__global__ __launch_bounds__(256, 4) void proj32(
    const float* __restrict__ x, const unsigned short* __restrict__ wt,
    unsigned short* __restrict__ qb, unsigned short* __restrict__ kb,
    unsigned short* __restrict__ vt)
{
    __shared__ alignas(16) unsigned short As[2][32 * LDK];   // [buf][row][k]
    __shared__ alignas(16) unsigned short Bs[2][64 * LDK];   // [buf][col][k]

    const int t = threadIdx.x, lane = t & 63, w = t >> 6;
    const int blk = blockIdx.x;
    const int mat = blk % 3;
    const int row0 = (blk / 3) * 32;
    const int wr = (w >> 1) * 16, wc = (w & 1) * 32;
    const int fr = lane & 15, ko = (lane >> 4) * 8;

    const int ar0 = t >> 4, akc = (t & 15) * 4;   // A: rows ar0, ar0+16
    const int bc0 = t >> 3, bkc = (t & 7) * 8;    // B: cols bc0, bc0+32

    const float* xp = x + (size_t)(row0 + ar0) * C_ + akc;
    const unsigned short* wp = wt + (size_t)(mat * 64 + bc0) * C_ + bkc;

    f32x4 pa[2];
    u16x8 pb[2];

    // prologue: tile 0
    pa[0] = *(const f32x4*)(xp);
    pa[1] = *(const f32x4*)(xp + (size_t)16 * C_);
    pb[0] = *(const u16x8*)(wp);
    pb[1] = *(const u16x8*)(wp + (size_t)32 * C_);
    #pragma unroll
    for (int i = 0; i < 2; ++i) {
        u16x4 bv;
        bv.x = f2bf(pa[i].x); bv.y = f2bf(pa[i].y);
        bv.z = f2bf(pa[i].z); bv.w = f2bf(pa[i].w);
        *(u16x4*)&As[0][(ar0 + i * 16) * LDK + akc] = bv;
        *(u16x8*)&Bs[0][(bc0 + i * 32) * LDK + bkc] = pb[i];
    }

    f32x4 acc[2];
    acc[0] = (f32x4){0.f, 0.f, 0.f, 0.f};
    acc[1] = (f32x4){0.f, 0.f, 0.f, 0.f};

    for (int it = 0; it < 16; ++it) {
        __syncthreads();
        const int cur = it & 1;
        if (it < 15) {   // issue next tile's loads NOW; stored after compute
            const float* xn = xp + (it + 1) * 64;
            const unsigned short* wn = wp + (it + 1) * 64;
            pa[0] = *(const f32x4*)(xn);
            pa[1] = *(const f32x4*)(xn + (size_t)16 * C_);
            pb[0] = *(const u16x8*)(wn);
            pb[1] = *(const u16x8*)(wn + (size_t)32 * C_);
        }
        const unsigned short* A = &As[cur][0];
        const unsigned short* Bb = &Bs[cur][0];
        #pragma unroll
        for (int ks = 0; ks < 2; ++ks) {
            s16x8 a0 = *(const s16x8*)&A[(wr + fr) * LDK + ks * 32 + ko];
            s16x8 b0 = *(const s16x8*)&Bb[(wc + fr) * LDK + ks * 32 + ko];
            s16x8 b1 = *(const s16x8*)&Bb[(wc + 16 + fr) * LDK + ks * 32 + ko];
            acc[0] = __builtin_amdgcn_mfma_f32_16x16x32_bf16(a0, b0, acc[0], 0, 0, 0);
            acc[1] = __builtin_amdgcn_mfma_f32_16x16x32_bf16(a0, b1, acc[1], 0, 0, 0);
        }
        if (it < 15) {
            const int nxt = cur ^ 1;
            #pragma unroll
            for (int i = 0; i < 2; ++i) {
                u16x4 bv;
                bv.x = f2bf(pa[i].x); bv.y = f2bf(pa[i].y);
                bv.z = f2bf(pa[i].z); bv.w = f2bf(pa[i].w);
                *(u16x4*)&As[nxt][(ar0 + i * 16) * LDK + akc] = bv;
                *(u16x8*)&Bs[nxt][(bc0 + i * 32) * LDK + bkc] = pb[i];
            }
        }
    }

    // ---- epilogue. C/D: col = fr, row = hi4*4 + j (within 16x16 frag) ----
    const int hi4 = lane >> 4;
    if (mat < 2) {
        unsigned short* outb = (mat == 0) ? qb : kb;
        #pragma unroll
        for (int ni = 0; ni < 2; ++ni)
            #pragma unroll
            for (int j = 0; j < 4; ++j) {
                int row = row0 + wr + hi4 * 4 + j;
                int col = wc + ni * 16 + fr;
                outb[(size_t)row * H_ + col] = f2bf(acc[ni][j]);
            }
    } else {
        // transpose V tile 32x64 -> vt[b][h][t]; Tr stride 40 (16B-aligned reads)
        __syncthreads();
        unsigned short* Tr = &As[0][0];   // 64*40 = 2560 shorts <= 4608
        #pragma unroll
        for (int ni = 0; ni < 2; ++ni)
            #pragma unroll
            for (int j = 0; j < 4; ++j) {
                int h = wc + ni * 16 + fr;
                int r = wr + hi4 * 4 + j;
                Tr[h * 40 + r] = f2bf(acc[ni][j]);
            }
        __syncthreads();
        int h = t >> 2, tg = (t & 3) * 8;
        int bb = row0 >> 11, trow = row0 & 2047;
        u16x8 vv = *(const u16x8*)&Tr[h * 40 + tg];
        *(u16x8*)&vt[(size_t)bb * H_ * T_ + (size_t)h * T_ + trow + tg] = vv;
    }
}

// ---------------- MFMA flash attention, R12 tuning ----------------
// Changes vs R10: (1) Ps row stride 72 (bank = 4*fr+... — fixes the 1.6M
// conflicts R11 measured); (2) Ps/Os LDS union + barrier (52 -> 38 KB ->
// 4 blocks/CU); (3) hoisted K/V pointers with imm offsets (VALU cut).
__global__ __launch_bounds__(512, 4) void attn_mfma(
    const unsigned short* __restrict__ qb, const unsigned short* __restrict__ kb,
    const unsigned short* __restrict__ vt, float* __restrict__ out)
{
    __shared__ alignas(16) unsigned char UB[36864];  // Ps (loop) / Os (epilogue)
    __shared__ float Mm[8][16];
    __shared__ float Ll[8][16];

    const int t = threadIdx.x, lane = t & 63, w = t >> 6;
    const int fr = lane & 15, hi4 = lane >> 4;
    const int blk = blockIdx.x;
    const int b = blk & 3;
    const int qt = 127 - (blk >> 2);     // big q-tiles dispatch first
    const int qbase = qt * 16;

    const unsigned short* qp = qb + ((size_t)b * T_ + qbase) * H_;
    const unsigned short* kp = kb + (size_t)b * T_ * H_;
    const unsigned short* vp = vt + (size_t)b * H_ * T_;

    // Q frag: lane supplies Q[q=fr][k=8*hi4..+7] — B-operand of mfma(K,Q)
    s16x8 qf0 = *(const s16x8*)&qp[fr * H_ + hi4 * 8];
    s16x8 qf1 = *(const s16x8*)&qp[fr * H_ + 32 + hi4 * 8];

    const int nt = (qbase + 79) >> 6;    // tiles covering keys 0..qbase+15
    const int per = (nt + 7) >> 3;
    const int tb = w * per;
    int te = tb + per; if (te > nt) te = nt;

    float m = NEG_, l = 0.f;
    f32x4 o[4];
    #pragma unroll
    for (int hf = 0; hf < 4; ++hf) o[hf] = (f32x4){0.f, 0.f, 0.f, 0.f};

    unsigned short* P = (unsigned short*)UB + w * 1152;   // [16][72] per wave
    const int swz = (fr & 3) << 4;
    const int qrow = qbase + fr;

    // hoisted, loop-carried pointers (lane terms folded once)
    const unsigned short* kp0 = kp + (size_t)tb * 4096 + fr * H_ + hi4 * 8;  // keys n=0,1
    const unsigned short* kp2 = kp0 + 2048;                                  // keys n=2,3
    const unsigned short* vq0 = vp + (size_t)(fr) * T_      + tb * 64 + hi4 * 8;
    const unsigned short* vq1 = vp + (size_t)(16 + fr) * T_ + tb * 64 + hi4 * 8;
    const unsigned short* vq2 = vp + (size_t)(32 + fr) * T_ + tb * 64 + hi4 * 8;
    const unsigned short* vq3 = vp + (size_t)(48 + fr) * T_ + tb * 64 + hi4 * 8;

    for (int kt = tb; kt < te; ++kt) {
        const int kt0 = kt << 6;

        // ---- QK^T swapped: D[row=key][col=q]; lane owns q-row fr, 16 keys ----
        f32x4 s[4];
        #pragma unroll
        for (int n = 0; n < 4; ++n) {
            const unsigned short* kr = ((n < 2) ? kp0 : kp2) + (n & 1) * 1024;
            s16x8 kf0 = *(const s16x8*)kr;
            s16x8 kf1 = *(const s16x8*)(kr + 32);
            f32x4 a = (f32x4){0.f, 0.f, 0.f, 0.f};
            a = __builtin_amdgcn_mfma_f32_16x16x32_bf16(kf0, qf0, a, 0, 0, 0);
            a = __builtin_amdgcn_mfma_f32_16x16x32_bf16(kf1, qf1, a, 0, 0, 0);
            s[n] = a;
        }

        // ---- issue V loads now; consumed after softmax ----
        s16x8 vf0a = *(const s16x8*)vq0, vf0b = *(const s16x8*)(vq0 + 32);
        s16x8 vf1a = *(const s16x8*)vq1, vf1b = *(const s16x8*)(vq1 + 32);
        s16x8 vf2a = *(const s16x8*)vq2, vf2b = *(const s16x8*)(vq2 + 32);
        s16x8 vf3a = *(const s16x8*)vq3, vf3b = *(const s16x8*)(vq3 + 32);

        kp0 += 4096; kp2 += 4096;
        vq0 += 64; vq1 += 64; vq2 += 64; vq3 += 64;

        // ---- causal mask in raw domain (boundary tiles only) ----
        if (kt0 + 63 > qbase) {
            #pragma unroll
            for (int n = 0; n < 4; ++n)
                #pragma unroll
                for (int j = 0; j < 4; ++j) {
                    int key = kt0 + n * 16 + hi4 * 4 + j;
                    s[n][j] = (key > qrow) ? NEG_ : s[n][j];
                }
        }

        // ---- defer-max online softmax ----
        float mxl = fmaxf(fmaxf(fmaxf(fmaxf(s[0][0], s[0][1]), fmaxf(s[0][2], s[0][3])),
                                fmaxf(fmaxf(s[1][0], s[1][1]), fmaxf(s[1][2], s[1][3]))),
                          fmaxf(fmaxf(fmaxf(s[2][0], s[2][1]), fmaxf(s[2][2], s[2][3])),
                                fmaxf(fmaxf(s[3][0], s[3][1]), fmaxf(s[3][2], s[3][3]))));
        if (!__all(mxl - m <= THRRAW_)) {
            float mx = fmaxf(mxl, __shfl_xor(mxl, 16));
            mx = fmaxf(mx, __shfl_xor(mx, 32));
            float mn = fmaxf(m, mx);
            float corr = exp2f((m - mn) * K2_);
            m = mn;
            l *= corr;
            #pragma unroll
            for (int j = 0; j < 4; ++j) {
                float cj = __shfl(corr, (lane & 48) + hi4 * 4 + j);
                o[0][j] *= cj; o[1][j] *= cj; o[2][j] *= cj; o[3][j] *= cj;
            }
        }
        const float nmk = -m * K2_;
        float sum = 0.f;
        #pragma unroll
        for (int n = 0; n < 4; ++n)
            #pragma unroll
            for (int j = 0; j < 4; ++j) {
                float p = exp2f(fmaf(s[n][j], K2_, nmk));
                s[n][j] = p; sum += p;
            }
        sum += __shfl_xor(sum, 16);
        sum += __shfl_xor(sum, 32);
        l += sum;

        // ---- P -> per-wave LDS (stride 72: conflict-fixed), XOR-swizzled ----
        #pragma unroll
        for (int n = 0; n < 4; ++n) {
            u16x4 pk;
            pk.x = f2bf(s[n][0]); pk.y = f2bf(s[n][1]);
            pk.z = f2bf(s[n][2]); pk.w = f2bf(s[n][3]);
            *(u16x4*)&P[fr * 72 + ((n * 16 + hi4 * 4) ^ swz)] = pk;
        }
        s16x8 pa0 = *(const s16x8*)&P[fr * 72 + ((hi4 * 8) ^ swz)];
        s16x8 pa1 = *(const s16x8*)&P[fr * 72 + ((32 + hi4 * 8) ^ swz)];

        // ---- PV: A = P, B = Vt (preloaded) ----
        o[0] = __builtin_amdgcn_mfma_f32_16x16x32_bf16(pa0, vf0a, o[0], 0, 0, 0);
        o[0] = __builtin_amdgcn_mfma_f32_16x16x32_bf16(pa1, vf0b, o[0], 0, 0, 0);
        o[1] = __builtin_amdgcn_mfma_f32_16x16x32_bf16(pa0, vf1a, o[1], 0, 0, 0);
        o[1] = __builtin_amdgcn_mfma_f32_16x16x32_bf16(pa1, vf1b, o[1], 0, 0, 0);
        o[2] = __builtin_amdgcn_mfma_f32_16x16x32_bf16(pa0, vf2a, o[2], 0, 0, 0);
        o[2] = __builtin_amdgcn_mfma_f32_16x16x32_bf16(pa1, vf2b, o[2], 0, 0, 0);
        o[3] = __builtin_amdgcn_mfma_f32_16x16x32_bf16(pa0, vf3a, o[3], 0, 0, 0);
        o[3] = __builtin_amdgcn_mfma_f32_16x16x32_bf16(pa1, vf3b, o[3], 0, 0, 0);
    }

    // ---- all waves done with Ps; reuse UB as Os ----
    __syncthreads();
    float* Ob = (float*)UB;   // Os[w][16][68]
    if (hi4 == 0) { Mm[w][fr] = m; Ll[w][fr] = l; }
    #pragma unroll
    for (int hf = 0; hf < 4; ++hf)
        #pragma unroll
        for (int j = 0; j < 4; ++j)
            Ob[((size_t)w * 16 + hi4 * 4 + j) * 68 + hf * 16 + fr] = o[hf][j];
    __syncthreads();

    if (t < 256) {
        int qq = t >> 4, h0 = (t & 15) * 4;
        float M = NEG_;
        #pragma unroll
        for (int s8 = 0; s8 < 8; ++s8) M = fmaxf(M, Mm[s8][qq]);
        float L = 0.f;
        f32x4 r = (f32x4){0.f, 0.f, 0.f, 0.f};
        #pragma unroll
        for (int s8 = 0; s8 < 8; ++s8) {
            float e = exp2f((Mm[s8][qq] - M) * K2_);
            L += Ll[s8][qq] * e;
            f32x4 osv = *(const f32x4*)&Ob[((size_t)s8 * 16 + qq) * 68 + h0];
            r.x = fmaf(osv.x, e, r.x);
            r.y = fmaf(osv.y, e, r.y);
            r.z = fmaf(osv.z, e, r.z);
            r.w = fmaf(osv.w, e, r.w);
        }
        float il = 1.0f / L;
        r.x *= il; r.y *= il; r.z *= il; r.w *= il;
        *(f32x4*)&out[((size_t)b * T_ + qbase + qq) * H_ + h0] = r;
    }
}

extern "C" void kernel_launch(void* const* d_in, const int* in_sizes, int n_in,
                              void* d_out, int out_size, void* d_ws, size_t ws_size,
                              hipStream_t stream) {
    const float* x  = (const float*)d_in[0];
    const float* Wq = (const float*)d_in[1];
    const float* Wk = (const float*)d_in[2];
    const float* Wv = (const float*)d_in[3];
    float* outp = (float*)d_out;

    unsigned short* base = (unsigned short*)d_ws;
    unsigned short* qbw = base;                    // [8192][64]
    unsigned short* kbw = base + 524288;           // [8192][64]
    unsigned short* vtw = base + 1048576;          // [4][64][2048]
    unsigned short* wtw = base + 1572864;          // [192][1024]

    wprep<<<96, 256, 0, stream>>>(Wq, Wk, Wv, wtw);
    proj32<<<(B_ * T_ / 32) * 3, 256, 0, stream>>>(x, wtw, qbw, kbw, vtw);
    attn_mfma<<<B_ * (T_ / 16), 512, 0, stream>>>(qbw, kbw, vtw, outp);
}